// Round 1
// baseline (153.643 us; speedup 1.0000x reference)
//
#include <hip/hip_runtime.h>
#include <hip/hip_bf16.h>
#include <stdint.h>

// SSMBlock: x -> silu(x Wg^T) -> s = xg Wsp^T -> scan(decay) -> out = states WcT^T + xg W2^T + b_out
// All GEMMs: bf16 MFMA 16x16x32, C = A[M,K] * W[N,K]^T (gemm_bt pattern).

typedef __bf16 bf16_t;
typedef bf16_t bf16x8 __attribute__((ext_vector_type(8)));
typedef bf16_t bf16x4 __attribute__((ext_vector_type(4)));
typedef float  f32x4  __attribute__((ext_vector_type(4)));

static __device__ __forceinline__ void async_copy16(bf16_t* lds, const bf16_t* g) {
    __builtin_amdgcn_global_load_lds((const __attribute__((address_space(1))) void*)g,
                                     (__attribute__((address_space(3))) void*)lds, 16, 0, 0);
}

// 128x128 tile, BK=32, 256 threads = 4 waves (2x2), each wave 64x64 via 4x4 MFMA frags.
// LDS k-sliced [kc][row][8] so global_load_lds dest is linear in lane order (no swizzle
// needed) and frag ds_read_b128 is bank-balanced.
// MODE: 0 = f32 out (+bias), 1 = bf16 out (+bias), 2 = silu -> bf16 (+bias)
template <int MODE>
__global__ __launch_bounds__(256, 2) void gemm_bt(
    const bf16_t* __restrict__ A0, const bf16_t* __restrict__ W0,
    const bf16_t* __restrict__ A1, const bf16_t* __restrict__ W1,
    const float* __restrict__ bias, void* __restrict__ outp,
    int M, int Nw, int K, int nph)
{
    __shared__ bf16_t As[4 * 128 * 8];
    __shared__ bf16_t Bs[4 * 128 * 8];
    const int tid = threadIdx.x;
    const int tN = Nw >> 7;
    const int mtile = blockIdx.x / tN, ntile = blockIdx.x % tN;
    const int m0 = mtile << 7, n0 = ntile << 7;
    const int l = tid & 63, w = tid >> 6;
    const int wr = w >> 1, wc = w & 1;
    const int lr = l & 15, kc = l >> 4;

    const f32x4 z = {0.f, 0.f, 0.f, 0.f};
    f32x4 acc[4][4];
    #pragma unroll
    for (int i = 0; i < 4; ++i)
        #pragma unroll
        for (int j = 0; j < 4; ++j) acc[i][j] = z;

    for (int ph = 0; ph < nph; ++ph) {
        const bf16_t* Ap = ph ? A1 : A0;
        const bf16_t* Wp = ph ? W1 : W0;
        const int nks = K >> 5;
        for (int ks = 0; ks < nks; ++ks) {
            if (ph | ks) __syncthreads();   // protect LDS before overwrite
            const int k0 = ks << 5;
            #pragma unroll
            for (int j = 0; j < 2; ++j) {
                const int q = j * 256 + tid;          // chunk id, LDS byte = q*16
                const int c = q >> 7, row = q & 127;  // k-slice, tile row
                // wave-uniform LDS base; HW adds lane*16
                async_copy16(As + (j * 256 + w * 64) * 8,
                             Ap + (size_t)(m0 + row) * K + k0 + c * 8);
                async_copy16(Bs + (j * 256 + w * 64) * 8,
                             Wp + (size_t)(n0 + row) * K + k0 + c * 8);
            }
            __syncthreads();  // drains vmcnt before reads
            bf16x8 a[4], b[4];
            #pragma unroll
            for (int i = 0; i < 4; ++i)
                a[i] = *(const bf16x8*)(As + (kc * 128 + wr * 64 + i * 16 + lr) * 8);
            #pragma unroll
            for (int j = 0; j < 4; ++j)
                b[j] = *(const bf16x8*)(Bs + (kc * 128 + wc * 64 + j * 16 + lr) * 8);
            #pragma unroll
            for (int i = 0; i < 4; ++i)
                #pragma unroll
                for (int j = 0; j < 4; ++j)
                    acc[i][j] = __builtin_amdgcn_mfma_f32_16x16x32_bf16(a[i], b[j], acc[i][j], 0, 0, 0);
        }
    }

    // C/D layout: col = lane&15, row = (lane>>4)*4 + reg   [verified m89/m91]
    float*  outF = (float*)outp;
    bf16_t* outB = (bf16_t*)outp;
    #pragma unroll
    for (int i = 0; i < 4; ++i) {
        const int row = m0 + wr * 64 + i * 16 + kc * 4;
        #pragma unroll
        for (int j = 0; j < 4; ++j) {
            const int col = n0 + wc * 64 + j * 16 + lr;
            const float bv = bias ? bias[col] : 0.f;
            #pragma unroll
            for (int r = 0; r < 4; ++r) {
                float v = acc[i][j][r] + bv;
                size_t idx = (size_t)(row + r) * Nw + col;
                if (MODE == 0)      outF[idx] = v;
                else if (MODE == 1) outB[idx] = (bf16_t)v;
                else { float sv = v / (1.f + expf(-v)); outB[idx] = (bf16_t)sv; }
            }
        }
    }
}

__global__ void prep_weights(const float* __restrict__ Wg, const float* __restrict__ Wsp,
                             const float* __restrict__ Wo, const float* __restrict__ Dp,
                             bf16_t* __restrict__ Wg_bf, bf16_t* __restrict__ Wsp_bf,
                             bf16_t* __restrict__ Wo_bf, bf16_t* __restrict__ W2_bf)
{
    int i = blockIdx.x * 256 + threadIdx.x;   // 512*512 threads
    Wg_bf[i]  = (bf16_t)Wg[i];
    Wsp_bf[i] = (bf16_t)Wsp[i];
    float wo  = Wo[i];
    Wo_bf[i]  = (bf16_t)wo;
    W2_bf[i]  = (bf16_t)(wo * Dp[i & 511]);   // W2[d',d] = W_out[d',d]*D[d]
}

__global__ void convert_x(const float4* __restrict__ x, bf16x4* __restrict__ xb)
{
    int i = blockIdx.x * 256 + threadIdx.x;
    float4 v = x[i];
    bf16x4 o;
    o[0] = (bf16_t)v.x; o[1] = (bf16_t)v.y; o[2] = (bf16_t)v.z; o[3] = (bf16_t)v.w;
    xb[i] = o;
}

__global__ void compute_decay(const float* __restrict__ A_log, float* __restrict__ decay)
{
    int d = blockIdx.x * 4 + (threadIdx.x >> 6);   // one wave per row
    int l = threadIdx.x & 63;
    const float* row = A_log + (size_t)d * 512;
    float s = 0.f;
    for (int k = l; k < 512; k += 64) s += expf(row[k]);
    #pragma unroll
    for (int off = 32; off > 0; off >>= 1) s += __shfl_down(s, off);
    if (l == 0) decay[d] = expf(-s * (1.f / 512.f));  // exp(mean(-exp(A_log)))
}

// ---- chunked scan: S=4096 -> 64 chunks x 64 steps, per (b,n) lane ----
__global__ void scan_partial(const bf16_t* __restrict__ s, const float* __restrict__ decay,
                             float* __restrict__ carry)
{
    int g = blockIdx.x * 256 + threadIdx.x;       // B*N*64 = 131072
    int n = g & 511, ch = (g >> 9) & 63, b = g >> 15;
    float dec = decay[n];
    const bf16_t* sp = s + (size_t)(b * 4096 + ch * 64) * 512 + n;
    float st = 0.f;
    #pragma unroll 8
    for (int i = 0; i < 64; ++i) st = st * dec + (float)sp[(size_t)i * 512];
    carry[(size_t)(b * 64 + ch) * 512 + n] = st;
}

__global__ void scan_carry(const float* __restrict__ carry, const float* __restrict__ decay,
                           const float* __restrict__ state0,
                           float* __restrict__ exc, float* __restrict__ state_f)
{
    int g = blockIdx.x * 256 + threadIdx.x;       // B*N = 2048
    int n = g & 511, b = g >> 9;
    float dec = decay[n];
    float d64 = dec;
    #pragma unroll
    for (int t = 0; t < 6; ++t) d64 *= d64;       // dec^64 via squaring
    float st = state0[g];
    for (int ch = 0; ch < 64; ++ch) {
        size_t idx = (size_t)(b * 64 + ch) * 512 + n;
        exc[idx] = st;                             // exclusive carry-in per chunk
        st = st * d64 + carry[idx];
    }
    state_f[g] = st;                               // final state -> d_out tail
}

__global__ void scan_final(const bf16_t* __restrict__ s, const float* __restrict__ decay,
                           const float* __restrict__ exc, bf16_t* __restrict__ states)
{
    int g = blockIdx.x * 256 + threadIdx.x;       // B*N*64
    int n = g & 511, ch = (g >> 9) & 63, b = g >> 15;
    float dec = decay[n];
    float st = exc[(size_t)(b * 64 + ch) * 512 + n];
    size_t base = (size_t)(b * 4096 + ch * 64) * 512 + n;
    #pragma unroll 8
    for (int i = 0; i < 64; ++i) {
        st = st * dec + (float)s[base + (size_t)i * 512];
        states[base + (size_t)i * 512] = (bf16_t)st;
    }
}

extern "C" void kernel_launch(void* const* d_in, const int* in_sizes, int n_in,
                              void* d_out, int out_size, void* d_ws, size_t ws_size,
                              hipStream_t stream)
{
    const float* x      = (const float*)d_in[0];
    const float* state0 = (const float*)d_in[1];
    const float* W_gate = (const float*)d_in[2];
    const float* b_gate = (const float*)d_in[3];
    const float* W_sp   = (const float*)d_in[4];
    const float* b_sp   = (const float*)d_in[5];
    const float* W_out  = (const float*)d_in[6];
    const float* b_out  = (const float*)d_in[7];
    const float* A_log  = (const float*)d_in[8];
    const float* D_par  = (const float*)d_in[9];
    float* out = (float*)d_out;

    // workspace layout (~51.5 MB)
    char* ws = (char*)d_ws;
    bf16_t* x_bf   = (bf16_t*)ws;                     // 16 MB, reused for states
    bf16_t* states = x_bf;
    bf16_t* xg_bf  = (bf16_t*)(ws + (16u << 20));     // 16 MB
    bf16_t* s_bf   = (bf16_t*)(ws + (32u << 20));     // 16 MB
    bf16_t* Wg_bf  = (bf16_t*)(ws + (48u << 20));     // 5 x 512 KB weights
    bf16_t* Wsp_bf = Wg_bf + 262144;
    bf16_t* Wo_bf  = Wg_bf + 2 * 262144;
    bf16_t* W2_bf  = Wg_bf + 3 * 262144;
    bf16_t* WcT_bf = Wg_bf + 4 * 262144;
    float*  carry  = (float*)(Wg_bf + 5 * 262144);    // 512 KB
    float*  exc    = carry + 131072;                  // 512 KB
    float*  decay  = exc + 131072;                    // 2 KB

    prep_weights<<<dim3(1024), dim3(256), 0, stream>>>(W_gate, W_sp, W_out, D_par,
                                                       Wg_bf, Wsp_bf, Wo_bf, W2_bf);
    compute_decay<<<dim3(128), dim3(256), 0, stream>>>(A_log, decay);
    convert_x<<<dim3(8192), dim3(256), 0, stream>>>((const float4*)x, (bf16x4*)x_bf);

    // WcT[d',n] = sum_d W_out[d',d] * W_sp[n,d]
    gemm_bt<1><<<dim3(16), dim3(256), 0, stream>>>(
        Wo_bf, Wsp_bf, (const bf16_t*)nullptr, (const bf16_t*)nullptr,
        (const float*)nullptr, (void*)WcT_bf, 512, 512, 512, 1);
    // xg = silu(x W_gate^T + b_gate)
    gemm_bt<2><<<dim3(512), dim3(256), 0, stream>>>(
        x_bf, Wg_bf, (const bf16_t*)nullptr, (const bf16_t*)nullptr,
        b_gate, (void*)xg_bf, 16384, 512, 512, 1);
    // s = xg W_sp^T + b_sp
    gemm_bt<1><<<dim3(512), dim3(256), 0, stream>>>(
        xg_bf, Wsp_bf, (const bf16_t*)nullptr, (const bf16_t*)nullptr,
        b_sp, (void*)s_bf, 16384, 512, 512, 1);

    scan_partial<<<dim3(512), dim3(256), 0, stream>>>(s_bf, decay, carry);
    scan_carry<<<dim3(8), dim3(256), 0, stream>>>(carry, decay, state0, exc, out + 8388608);
    scan_final<<<dim3(512), dim3(256), 0, stream>>>(s_bf, decay, exc, states);

    // out = states WcT^T + xg W2^T + b_out   (dual-phase accumulate)
    gemm_bt<0><<<dim3(512), dim3(256), 0, stream>>>(
        states, WcT_bf, xg_bf, W2_bf, b_out, (void*)out, 16384, 512, 512, 2);
}